// Round 3
// baseline (206.433 us; speedup 1.0000x reference)
//
#include <hip/hip_runtime.h>
#include <math.h>

#define IN_C 256
#define SE_C 16
#define BATCH 32
#define HW 3136    // 56*56
#define HW4 784    // HW/4 float4s per plane

// ---------------------------------------------------------------------------
// Kernel 1: global average pool. One block per (b,c) plane (8192 blocks).
// Each plane = 3136 floats = 784 float4. 256 threads: 3 full float4 rounds
// (768) + 16-thread tail. Coalesced 16B/lane loads -> HBM-read-bound.
// ---------------------------------------------------------------------------
__global__ __launch_bounds__(256) void se_pool(const float* __restrict__ x,
                                               float* __restrict__ s) {
    const int plane = blockIdx.x;  // b*IN_C + c
    const float4* xp = (const float4*)(x + (size_t)plane * HW);
    const int t = threadIdx.x;

    float sum = 0.f;
#pragma unroll
    for (int i = 0; i < 3; ++i) {
        float4 v = xp[t + i * 256];
        sum += (v.x + v.y) + (v.z + v.w);
    }
    if (t < HW4 - 768) {  // tail: 16 float4
        float4 v = xp[768 + t];
        sum += (v.x + v.y) + (v.z + v.w);
    }

    // wave64 butterfly reduce
#pragma unroll
    for (int off = 32; off > 0; off >>= 1) sum += __shfl_down(sum, off);

    __shared__ float wsum[4];
    if ((t & 63) == 0) wsum[t >> 6] = sum;
    __syncthreads();
    if (t == 0) {
        float tot = (wsum[0] + wsum[1]) + (wsum[2] + wsum[3]);
        s[plane] = tot * (1.0f / (float)HW);
    }
}

// ---------------------------------------------------------------------------
// Kernel 2: squeeze FC (256->16, relu) + excite FC (16->256, sigmoid).
// One block per batch image (32 blocks x 256 threads). Latency-bound, tiny.
// ---------------------------------------------------------------------------
__global__ __launch_bounds__(256) void se_fc(const float* __restrict__ s,
                                             const float* __restrict__ w1,
                                             const float* __restrict__ b1,
                                             const float* __restrict__ w2,
                                             const float* __restrict__ b2,
                                             float* __restrict__ g) {
    const int b = blockIdx.x;
    const int t = threadIdx.x;

    __shared__ float sv[IN_C];
    __shared__ float h[SE_C];

    sv[t] = s[b * IN_C + t];
    __syncthreads();

    if (t < SE_C) {
        float acc = b1[t];
        const float* wrow = w1 + t * IN_C;
#pragma unroll 8
        for (int c = 0; c < IN_C; ++c) acc = fmaf(wrow[c], sv[c], acc);
        h[t] = fmaxf(acc, 0.f);
    }
    __syncthreads();

    float acc = b2[t];
    const float* wrow = w2 + t * SE_C;
#pragma unroll
    for (int e = 0; e < SE_C; ++e) acc = fmaf(wrow[e], h[e], acc);
    g[b * IN_C + t] = 1.0f / (1.0f + expf(-acc));
}

// ---------------------------------------------------------------------------
// Kernel 3: broadcast scale out = x * g[b,c]. One block per (b,c) plane:
// g[plane] is a wave-uniform scalar load done once; no integer divide in
// the hot loop. 3 full float4 rounds + 16-lane tail, same shape as se_pool.
// ---------------------------------------------------------------------------
__global__ __launch_bounds__(256) void se_scale(const float* __restrict__ x,
                                                const float* __restrict__ g,
                                                float* __restrict__ out) {
    const int plane = blockIdx.x;  // b*IN_C + c
    const float4* xp = (const float4*)(x + (size_t)plane * HW);
    float4* op = (float4*)(out + (size_t)plane * HW);
    const int t = threadIdx.x;
    const float gv = g[plane];

#pragma unroll
    for (int i = 0; i < 3; ++i) {
        float4 v = xp[t + i * 256];
        v.x *= gv; v.y *= gv; v.z *= gv; v.w *= gv;
        op[t + i * 256] = v;
    }
    if (t < HW4 - 768) {  // tail: 16 float4
        float4 v = xp[768 + t];
        v.x *= gv; v.y *= gv; v.z *= gv; v.w *= gv;
        op[768 + t] = v;
    }
}

extern "C" void kernel_launch(void* const* d_in, const int* in_sizes, int n_in,
                              void* d_out, int out_size, void* d_ws, size_t ws_size,
                              hipStream_t stream) {
    const float* x  = (const float*)d_in[0];
    const float* w1 = (const float*)d_in[1];
    const float* b1 = (const float*)d_in[2];
    const float* w2 = (const float*)d_in[3];
    const float* b2 = (const float*)d_in[4];
    float* out = (float*)d_out;

    float* s = (float*)d_ws;            // 8192 floats (pooled means)
    float* g = s + BATCH * IN_C;        // 8192 floats (gates)

    se_pool<<<BATCH * IN_C, 256, 0, stream>>>(x, s);
    se_fc<<<BATCH, 256, 0, stream>>>(s, w1, b1, w2, b2, g);
    se_scale<<<BATCH * IN_C, 256, 0, stream>>>(x, g, out);
}

// Round 5
// 198.486 us; speedup vs baseline: 1.0400x; 1.0400x over previous
//
#include <hip/hip_runtime.h>
#include <math.h>

#define IN_C 256
#define SE_C 16
#define BATCH 32
#define HW 3136    // 56*56
#define HW4 784    // HW/4 float4s per plane

typedef float f32x4 __attribute__((ext_vector_type(4)));

// ---------------------------------------------------------------------------
// Kernel 1: global average pool. One block per (b,c) plane (8192 blocks).
// Each plane = 3136 floats = 784 float4. 256 threads: 3 full float4 rounds
// (768) + 16-thread tail. Coalesced 16B/lane loads -> HBM-read-bound.
// ---------------------------------------------------------------------------
__global__ __launch_bounds__(256) void se_pool(const float* __restrict__ x,
                                               float* __restrict__ s) {
    const int plane = blockIdx.x;  // b*IN_C + c
    const f32x4* xp = (const f32x4*)(x + (size_t)plane * HW);
    const int t = threadIdx.x;

    float sum = 0.f;
#pragma unroll
    for (int i = 0; i < 3; ++i) {
        f32x4 v = xp[t + i * 256];
        sum += (v.x + v.y) + (v.z + v.w);
    }
    if (t < HW4 - 768) {  // tail: 16 float4
        f32x4 v = xp[768 + t];
        sum += (v.x + v.y) + (v.z + v.w);
    }

    // wave64 butterfly reduce
#pragma unroll
    for (int off = 32; off > 0; off >>= 1) sum += __shfl_down(sum, off);

    __shared__ float wsum[4];
    if ((t & 63) == 0) wsum[t >> 6] = sum;
    __syncthreads();
    if (t == 0) {
        float tot = (wsum[0] + wsum[1]) + (wsum[2] + wsum[3]);
        s[plane] = tot * (1.0f / (float)HW);
    }
}

// ---------------------------------------------------------------------------
// Kernel 2: fused fc + scale. One block per (b,c) plane (8192 blocks).
// Each block recomputes the squeeze/excite gate for ITS plane:
//   h[e] = relu(b1[e] + dot(w1[e,:], s[b,:]))   (16x16 thread split + shfl16)
//   gv   = sigmoid(b2[c] + dot(w2[c,:], h))     (wave-uniform, 16 FMAs)
// Redundant FC compute = 8192 blocks x ~4 KFLOP = 34 MFLOP total (trivial);
// s (1 KB) and w1 (16 KB) are L2/L3-hot after the first blocks.
// Then scales its plane with NONTEMPORAL stores so the 103 MB output write
// doesn't evict x from L3 (x is re-read here after se_pool warmed it).
// ---------------------------------------------------------------------------
__global__ __launch_bounds__(256) void se_fcscale(const float* __restrict__ x,
                                                  const float* __restrict__ s,
                                                  const float* __restrict__ w1,
                                                  const float* __restrict__ b1,
                                                  const float* __restrict__ w2,
                                                  const float* __restrict__ b2,
                                                  float* __restrict__ out) {
    const int plane = blockIdx.x;      // b*IN_C + c
    const int b = plane >> 8;          // /IN_C
    const int c = plane & (IN_C - 1);
    const int t = threadIdx.x;

    __shared__ float hl[SE_C];

    // --- squeeze FC: thread t = e*16 + i; partial over channels i+16k ---
    {
        const int e = t >> 4;
        const int i = t & 15;
        const float* srow = s + b * IN_C;
        const float* wrow = w1 + e * IN_C;
        float p = 0.f;
#pragma unroll
        for (int k = 0; k < 16; ++k) {
            const int ch = i + k * 16;
            p = fmaf(wrow[ch], srow[ch], p);
        }
        // reduce across the 16-lane subgroup (i dimension)
#pragma unroll
        for (int off = 8; off > 0; off >>= 1) p += __shfl_down(p, off, 16);
        if (i == 0) hl[e] = fmaxf(p + b1[e], 0.f);
    }
    __syncthreads();

    // --- excite FC for this plane's channel only (wave-uniform) ---
    float acc = b2[c];
    const float* w2row = w2 + c * SE_C;
#pragma unroll
    for (int e = 0; e < SE_C; ++e) acc = fmaf(w2row[e], hl[e], acc);
    const float gv = 1.0f / (1.0f + expf(-acc));

    // --- scale this plane, nontemporal stores (out never re-read) ---
    const f32x4* xp = (const f32x4*)(x + (size_t)plane * HW);
    f32x4* op = (f32x4*)(out + (size_t)plane * HW);
#pragma unroll
    for (int i = 0; i < 3; ++i) {
        f32x4 v = xp[t + i * 256] * gv;
        __builtin_nontemporal_store(v, &op[t + i * 256]);
    }
    if (t < HW4 - 768) {  // tail: 16 float4
        f32x4 v = xp[768 + t] * gv;
        __builtin_nontemporal_store(v, &op[768 + t]);
    }
}

extern "C" void kernel_launch(void* const* d_in, const int* in_sizes, int n_in,
                              void* d_out, int out_size, void* d_ws, size_t ws_size,
                              hipStream_t stream) {
    const float* x  = (const float*)d_in[0];
    const float* w1 = (const float*)d_in[1];
    const float* b1 = (const float*)d_in[2];
    const float* w2 = (const float*)d_in[3];
    const float* b2 = (const float*)d_in[4];
    float* out = (float*)d_out;

    float* s = (float*)d_ws;  // 8192 floats (pooled means)

    se_pool<<<BATCH * IN_C, 256, 0, stream>>>(x, s);
    se_fcscale<<<BATCH * IN_C, 256, 0, stream>>>(x, s, w1, b1, w2, b2, out);
}